// Round 1
// baseline (2656.594 us; speedup 1.0000x reference)
//
#include <hip/hip_runtime.h>
#include <hip/hip_bf16.h>

#define IN_DIM 128
#define HID    64
#define OUT_DIM 40

// ---------------- degree histogram ----------------
__global__ void deg_count(const int* __restrict__ dst, int e, float* __restrict__ deg) {
    int i = blockIdx.x * blockDim.x + threadIdx.x;
    if (i < e) atomicAdd(&deg[dst[i]], 1.0f);
}

// dinv = rsqrt(deg + 1)   (the +1 is the self-loop)
__global__ void dinv_k(float* __restrict__ deg, int n) {
    int i = blockIdx.x * blockDim.x + threadIdx.x;
    if (i < n) deg[i] = rsqrtf(deg[i] + 1.0f);
}

// ---------------- GEMM1: hw1 = x @ W1 ; agg1 = dinv^2 * hw1 (self-loop init) ----
// block = 256 threads = 4 rows x 64 cols
__global__ void gemm1(const float* __restrict__ x, const float* __restrict__ W1,
                      const float* __restrict__ dinv,
                      float* __restrict__ hw1, float* __restrict__ agg1, int n) {
    __shared__ float Ws[IN_DIM * HID];   // 32 KB
    for (int i = threadIdx.x; i < IN_DIM * HID; i += blockDim.x) Ws[i] = W1[i];
    __syncthreads();
    int row = blockIdx.x * 4 + (threadIdx.x >> 6);
    int col = threadIdx.x & 63;
    if (row >= n) return;
    const float* xr = x + (size_t)row * IN_DIM;
    float acc = 0.f;
#pragma unroll 8
    for (int k = 0; k < IN_DIM; ++k) acc = fmaf(xr[k], Ws[k * HID + col], acc);
    size_t o = (size_t)row * HID + col;
    hw1[o] = acc;
    float di = dinv[row];
    agg1[o] = di * di * acc;
}

// ---------------- scatter1: agg1[dst] += norm * hw1[src], HID cols -------------
// 16 threads per edge, each handles one float4 (4 cols)
__global__ void scatter1(const int* __restrict__ src, const int* __restrict__ dst,
                         const float* __restrict__ dinv, const float* __restrict__ hw1,
                         float* __restrict__ agg1, int e) {
    int gid = blockIdx.x * blockDim.x + threadIdx.x;
    int eid = gid >> 4;
    int p   = gid & 15;
    if (eid >= e) return;
    int s = src[eid], d = dst[eid];
    float nrm = dinv[s] * dinv[d];
    const float4 v = *(const float4*)(hw1 + (size_t)s * HID + p * 4);
    float* o = agg1 + (size_t)d * HID + p * 4;
    atomicAdd(o + 0, nrm * v.x);
    atomicAdd(o + 1, nrm * v.y);
    atomicAdd(o + 2, nrm * v.z);
    atomicAdd(o + 3, nrm * v.w);
}

// ---------------- GEMM2: h = relu(agg1 + b1); hw2 = h @ W2; out = dinv^2*hw2 ----
// block = 320 threads = 8 rows x 40 cols
__global__ void gemm2(const float* __restrict__ aggin, const float* __restrict__ W2,
                      const float* __restrict__ b1, const float* __restrict__ dinv,
                      float* __restrict__ hw2, float* __restrict__ aggout, int n) {
    __shared__ float Ws[HID * OUT_DIM];   // 2560 floats
    __shared__ float hs[8][HID];          // 512 floats
    for (int i = threadIdx.x; i < HID * OUT_DIM; i += blockDim.x) Ws[i] = W2[i];
    int base = blockIdx.x * 8;
    for (int i = threadIdx.x; i < 8 * HID; i += blockDim.x) {
        int r = i >> 6, k = i & 63;
        int gr = base + r;
        float v = 0.f;
        if (gr < n) v = fmaxf(aggin[(size_t)gr * HID + k] + b1[k], 0.f);
        hs[r][k] = v;
    }
    __syncthreads();
    int lr  = threadIdx.x / OUT_DIM;      // 0..7
    int col = threadIdx.x - lr * OUT_DIM; // 0..39
    int row = base + lr;
    if (row >= n) return;
    float acc = 0.f;
#pragma unroll 8
    for (int k = 0; k < HID; ++k) acc = fmaf(hs[lr][k], Ws[k * OUT_DIM + col], acc);
    size_t o = (size_t)row * OUT_DIM + col;
    hw2[o] = acc;
    float di = dinv[row];
    aggout[o] = di * di * acc;
}

// ---------------- scatter2: out[dst] += norm * hw2[src], OUT_DIM cols -----------
// 10 threads per edge, each handles one float4 (4 cols)
__global__ void scatter2(const int* __restrict__ src, const int* __restrict__ dst,
                         const float* __restrict__ dinv, const float* __restrict__ hw2,
                         float* __restrict__ out, int e) {
    int gid = blockIdx.x * blockDim.x + threadIdx.x;
    int eid = gid / 10;
    int p   = gid - eid * 10;
    if (eid >= e) return;
    int s = src[eid], d = dst[eid];
    float nrm = dinv[s] * dinv[d];
    const float4 v = *(const float4*)(hw2 + (size_t)s * OUT_DIM + p * 4);
    float* o = out + (size_t)d * OUT_DIM + p * 4;
    atomicAdd(o + 0, nrm * v.x);
    atomicAdd(o + 1, nrm * v.y);
    atomicAdd(o + 2, nrm * v.z);
    atomicAdd(o + 3, nrm * v.w);
}

// ---------------- finalize: y = relu(agg2 + b2 + P*K*U); log_softmax ------------
// one wave (64 lanes) per row; block 256 = 4 rows
__global__ void finalize_k(float* __restrict__ out, const float* __restrict__ b2,
                           const float* __restrict__ P, const float* __restrict__ K,
                           const float* __restrict__ U, int n) {
    int row  = blockIdx.x * 4 + (threadIdx.x >> 6);
    int lane = threadIdx.x & 63;
    if (row >= n) return;
    float* rp = out + (size_t)row * OUT_DIM;
    float v = 0.f;
    float y = -INFINITY;
    if (lane < OUT_DIM) {
        v = rp[lane] + b2[lane] + P[lane] * K[lane] * U[lane];
        v = fmaxf(v, 0.f);
        y = v;
    }
    float m = y;
#pragma unroll
    for (int off = 32; off; off >>= 1) m = fmaxf(m, __shfl_xor(m, off));
    float ex = (lane < OUT_DIM) ? __expf(v - m) : 0.f;
    float s = ex;
#pragma unroll
    for (int off = 32; off; off >>= 1) s += __shfl_xor(s, off);
    float lse = m + __logf(s);
    if (lane < OUT_DIM) rp[lane] = v - lse;
}

extern "C" void kernel_launch(void* const* d_in, const int* in_sizes, int n_in,
                              void* d_out, int out_size, void* d_ws, size_t ws_size,
                              hipStream_t stream) {
    const float* x  = (const float*)d_in[0];
    const int*   ei = (const int*)d_in[1];
    const float* W1 = (const float*)d_in[2];
    const float* b1 = (const float*)d_in[3];
    const float* W2 = (const float*)d_in[4];
    const float* b2 = (const float*)d_in[5];
    const float* P  = (const float*)d_in[6];
    const float* K  = (const float*)d_in[7];
    const float* U  = (const float*)d_in[8];
    float* out = (float*)d_out;

    int n = in_sizes[0] / IN_DIM;   // 100000
    int e = in_sizes[1] / 2;        // 1600000
    const int* src = ei;
    const int* dst = ei + e;

    // workspace layout (floats): deg/dinv [n] | hw1 [n*HID] | agg1 [n*HID]
    float* deg  = (float*)d_ws;
    float* hw1  = deg + n;
    float* agg1 = hw1 + (size_t)n * HID;
    float* hw2  = hw1;   // reuse hw1 slot after scatter1 (n*OUT_DIM <= n*HID)

    hipMemsetAsync(deg, 0, (size_t)n * sizeof(float), stream);
    deg_count<<<(e + 255) / 256, 256, 0, stream>>>(dst, e, deg);
    dinv_k<<<(n + 255) / 256, 256, 0, stream>>>(deg, n);

    gemm1<<<(n + 3) / 4, 256, 0, stream>>>(x, W1, deg, hw1, agg1, n);
    scatter1<<<(int)(((size_t)e * 16 + 255) / 256), 256, 0, stream>>>(src, dst, deg, hw1, agg1, e);
    gemm2<<<(n + 7) / 8, 320, 0, stream>>>(agg1, W2, b1, deg, hw2, out, n);
    scatter2<<<(int)(((size_t)e * 10 + 255) / 256), 256, 0, stream>>>(src, dst, deg, hw2, out, e);
    finalize_k<<<(n + 3) / 4, 256, 0, stream>>>(out, b2, P, K, U, n);
}

// Round 2
// 914.190 us; speedup vs baseline: 2.9060x; 2.9060x over previous
//
#include <hip/hip_runtime.h>
#include <hip/hip_bf16.h>

#define IN_DIM 128
#define HID    64
#define OUT_DIM 40

// ---------------- CSR build: count, dinv, scan, bin ----------------
__global__ void count_k(const int* __restrict__ dst, int e, int* __restrict__ cnt) {
    int i = blockIdx.x * blockDim.x + threadIdx.x;
    if (i < e) atomicAdd(&cnt[dst[i]], 1);
}

__global__ void dinv_k(const int* __restrict__ cnt, float* __restrict__ dinv, int n) {
    int i = blockIdx.x * blockDim.x + threadIdx.x;
    if (i < n) dinv[i] = rsqrtf((float)cnt[i] + 1.0f);
}

// single-block exclusive scan of cnt[0..n) -> off[0..n], cursor copy
__global__ void scan_k(const int* __restrict__ cnt, int n,
                       int* __restrict__ off, int* __restrict__ cursor) {
    __shared__ int sums[1024];
    int t = threadIdx.x;
    int chunk = (n + 1023) >> 10;
    int beg = t * chunk, end = min(beg + chunk, n);
    int s = 0;
    for (int i = beg; i < end; ++i) s += cnt[i];
    sums[t] = s;
    __syncthreads();
    for (int ofs = 1; ofs < 1024; ofs <<= 1) {
        int add = (t >= ofs) ? sums[t - ofs] : 0;
        __syncthreads();
        sums[t] += add;
        __syncthreads();
    }
    int run = sums[t] - s;   // exclusive prefix of this chunk
    for (int i = beg; i < end; ++i) {
        int c = cnt[i];
        off[i] = run; cursor[i] = run;
        run += c;
    }
    if (t == 1023) off[n] = sums[1023];
}

__global__ void bin_k(const int* __restrict__ src, const int* __restrict__ dst, int e,
                      int* __restrict__ cursor, int* __restrict__ sorted) {
    int i = blockIdx.x * blockDim.x + threadIdx.x;
    if (i < e) {
        int d = dst[i];
        int pos = atomicAdd(&cursor[d], 1);
        sorted[pos] = src[i];
    }
}

// ---------------- GEMM1: hw1 = x @ W1 ----------------
// block = 512 threads = 8 rows x 64 cols
__global__ void gemm1(const float* __restrict__ x, const float* __restrict__ W1,
                      float* __restrict__ hw1, int n) {
    __shared__ float Ws[IN_DIM * HID];   // 32 KB
    for (int i = threadIdx.x; i < IN_DIM * HID; i += blockDim.x) Ws[i] = W1[i];
    __syncthreads();
    int row = blockIdx.x * 8 + (threadIdx.x >> 6);
    int col = threadIdx.x & 63;
    if (row >= n) return;
    const float* xr = x + (size_t)row * IN_DIM;
    float acc = 0.f;
#pragma unroll 8
    for (int k = 0; k < IN_DIM; ++k) acc = fmaf(xr[k], Ws[k * HID + col], acc);
    hw1[(size_t)row * HID + col] = acc;
}

// ---------------- gather1: h[d] = dinv^2*hw1[d] + sum norm*hw1[src] ------------
// one wave per dst node, lane = column (HID=64)
__global__ void gather1(const float* __restrict__ hw1, const float* __restrict__ dinv,
                        const int* __restrict__ off, const int* __restrict__ sorted,
                        float* __restrict__ agg, int n) {
    int wid  = blockIdx.x * (blockDim.x >> 6) + (threadIdx.x >> 6);
    int lane = threadIdx.x & 63;
    if (wid >= n) return;
    float dd = dinv[wid];
    float acc = dd * dd * hw1[(size_t)wid * HID + lane];
    int b = off[wid], en = off[wid + 1];
    for (int j = b; j < en; ++j) {
        int s = sorted[j];
        acc = fmaf(dd * dinv[s], hw1[(size_t)s * HID + lane], acc);
    }
    agg[(size_t)wid * HID + lane] = acc;
}

// ---------------- GEMM2: hw2 = relu(h + b1) @ W2 ----------------
// block = 320 threads = 8 rows x 40 cols
__global__ void gemm2(const float* __restrict__ h, const float* __restrict__ W2,
                      const float* __restrict__ b1, float* __restrict__ hw2, int n) {
    __shared__ float Ws[HID * OUT_DIM];
    __shared__ float hs[8][HID];
    for (int i = threadIdx.x; i < HID * OUT_DIM; i += blockDim.x) Ws[i] = W2[i];
    int base = blockIdx.x * 8;
    for (int i = threadIdx.x; i < 8 * HID; i += blockDim.x) {
        int r = i >> 6, k = i & 63;
        int gr = base + r;
        float v = 0.f;
        if (gr < n) v = fmaxf(h[(size_t)gr * HID + k] + b1[k], 0.f);
        hs[r][k] = v;
    }
    __syncthreads();
    int lr  = threadIdx.x / OUT_DIM;
    int col = threadIdx.x - lr * OUT_DIM;
    int row = base + lr;
    if (row >= n) return;
    float acc = 0.f;
#pragma unroll 8
    for (int k = 0; k < HID; ++k) acc = fmaf(hs[lr][k], Ws[k * OUT_DIM + col], acc);
    hw2[(size_t)row * OUT_DIM + col] = acc;
}

// ---------------- gather2 + finalize (bias + PKU + relu + log_softmax) ---------
// one wave per dst node, lanes 0..39 = columns
__global__ void gather2_fin(const float* __restrict__ hw2, const float* __restrict__ dinv,
                            const int* __restrict__ off, const int* __restrict__ sorted,
                            const float* __restrict__ b2, const float* __restrict__ P,
                            const float* __restrict__ Kv, const float* __restrict__ U,
                            float* __restrict__ out, int n) {
    int wid  = blockIdx.x * (blockDim.x >> 6) + (threadIdx.x >> 6);
    int lane = threadIdx.x & 63;
    if (wid >= n) return;
    float dd = dinv[wid];
    float acc = 0.f;
    if (lane < OUT_DIM) acc = dd * dd * hw2[(size_t)wid * OUT_DIM + lane];
    int b = off[wid], en = off[wid + 1];
    for (int j = b; j < en; ++j) {
        int s = sorted[j];
        float nrm = dd * dinv[s];
        if (lane < OUT_DIM) acc = fmaf(nrm, hw2[(size_t)s * OUT_DIM + lane], acc);
    }
    float v = 0.f, y = -INFINITY;
    if (lane < OUT_DIM) {
        v = fmaxf(acc + b2[lane] + P[lane] * Kv[lane] * U[lane], 0.f);
        y = v;
    }
    float m = y;
#pragma unroll
    for (int o = 32; o; o >>= 1) m = fmaxf(m, __shfl_xor(m, o));
    float ex = (lane < OUT_DIM) ? __expf(v - m) : 0.f;
    float s2 = ex;
#pragma unroll
    for (int o = 32; o; o >>= 1) s2 += __shfl_xor(s2, o);
    float lse = m + __logf(s2);
    if (lane < OUT_DIM) out[(size_t)wid * OUT_DIM + lane] = v - lse;
}

extern "C" void kernel_launch(void* const* d_in, const int* in_sizes, int n_in,
                              void* d_out, int out_size, void* d_ws, size_t ws_size,
                              hipStream_t stream) {
    const float* x  = (const float*)d_in[0];
    const int*   ei = (const int*)d_in[1];
    const float* W1 = (const float*)d_in[2];
    const float* b1 = (const float*)d_in[3];
    const float* W2 = (const float*)d_in[4];
    const float* b2 = (const float*)d_in[5];
    const float* P  = (const float*)d_in[6];
    const float* K  = (const float*)d_in[7];
    const float* U  = (const float*)d_in[8];
    float* out = (float*)d_out;

    int n = in_sizes[0] / IN_DIM;   // 100000
    int e = in_sizes[1] / 2;        // 1600000
    const int* src = ei;
    const int* dst = ei + e;

    // workspace layout:
    // cnt[n] | dinv[n] | off[n+1] | cursor[n] | sorted[e] | hw1[n*64] | agg1[n*64]
    int*   cnt    = (int*)d_ws;
    float* dinv   = (float*)(cnt + n);
    int*   off    = (int*)(dinv + n);
    int*   cursor = off + (n + 1);
    int*   sorted = cursor + n;
    float* hw1    = (float*)(sorted + e);
    float* agg1   = hw1 + (size_t)n * HID;
    float* hw2    = hw1;   // reuse hw1 slot after gather1 (n*OUT_DIM < n*HID)

    hipMemsetAsync(cnt, 0, (size_t)n * sizeof(int), stream);
    count_k<<<(e + 255) / 256, 256, 0, stream>>>(dst, e, cnt);
    dinv_k<<<(n + 255) / 256, 256, 0, stream>>>(cnt, dinv, n);
    scan_k<<<1, 1024, 0, stream>>>(cnt, n, off, cursor);
    bin_k<<<(e + 255) / 256, 256, 0, stream>>>(src, dst, e, cursor, sorted);

    gemm1<<<(n + 7) / 8, 512, 0, stream>>>(x, W1, hw1, n);
    gather1<<<(n + 3) / 4, 256, 0, stream>>>(hw1, dinv, off, sorted, agg1, n);
    gemm2<<<(n + 7) / 8, 320, 0, stream>>>(agg1, W2, b1, hw2, n);
    gather2_fin<<<(n + 3) / 4, 256, 0, stream>>>(hw2, dinv, off, sorted,
                                                 b2, P, K, U, out, n);
}

// Round 3
// 690.764 us; speedup vs baseline: 3.8459x; 1.3234x over previous
//
#include <hip/hip_runtime.h>
#include <hip/hip_bf16.h>

#define IN_DIM 128
#define HID    64
#define OUT_DIM 40

// ---------------- degree count ----------------
__global__ void count_k(const int* __restrict__ dst, int e, int* __restrict__ cnt) {
    int i = blockIdx.x * blockDim.x + threadIdx.x;
    if (i < e) atomicAdd(&cnt[dst[i]], 1);
}

__global__ void dinv_k(const int* __restrict__ cnt, float* __restrict__ dinv, int n) {
    int i = blockIdx.x * blockDim.x + threadIdx.x;
    if (i < n) dinv[i] = rsqrtf((float)cnt[i] + 1.0f);
}

// ---------------- hierarchical exclusive scan ----------------
// phase 1: each block scans 1024 elements (256 thr x 4), writes block sum
__global__ void scan_local(const int* __restrict__ cnt, int n,
                           int* __restrict__ off, int* __restrict__ bsum) {
    __shared__ int tmp[256];
    int t = threadIdx.x;
    int i0 = blockIdx.x * 1024 + t * 4;
    int c0 = (i0 + 0 < n) ? cnt[i0 + 0] : 0;
    int c1 = (i0 + 1 < n) ? cnt[i0 + 1] : 0;
    int c2 = (i0 + 2 < n) ? cnt[i0 + 2] : 0;
    int c3 = (i0 + 3 < n) ? cnt[i0 + 3] : 0;
    int s = c0 + c1 + c2 + c3;
    tmp[t] = s;
    __syncthreads();
    for (int ofs = 1; ofs < 256; ofs <<= 1) {
        int add = (t >= ofs) ? tmp[t - ofs] : 0;
        __syncthreads();
        tmp[t] += add;
        __syncthreads();
    }
    int run = tmp[t] - s;  // exclusive prefix within block
    if (i0 + 0 < n) off[i0 + 0] = run; run += c0;
    if (i0 + 1 < n) off[i0 + 1] = run; run += c1;
    if (i0 + 2 < n) off[i0 + 2] = run; run += c2;
    if (i0 + 3 < n) off[i0 + 3] = run;
    if (t == 255) bsum[blockIdx.x] = tmp[255];
}

// phase 2: one block scans the block sums (nb <= 1024), exclusive, sets off[n]
__global__ void scan_bsum(int* __restrict__ bsum, int nb, int n, int* __restrict__ off) {
    __shared__ int tmp[1024];
    int t = threadIdx.x;
    int v = (t < nb) ? bsum[t] : 0;
    tmp[t] = v;
    __syncthreads();
    for (int ofs = 1; ofs < 1024; ofs <<= 1) {
        int add = (t >= ofs) ? tmp[t - ofs] : 0;
        __syncthreads();
        tmp[t] += add;
        __syncthreads();
    }
    if (t < nb) bsum[t] = tmp[t] - v;   // exclusive prefix of block
    if (t == 1023) off[n] = tmp[1023];  // total
}

// phase 3: add block prefix, fill cursor copy
__global__ void scan_add(int* __restrict__ off, const int* __restrict__ bsum,
                         int n, int* __restrict__ cursor) {
    int i = blockIdx.x * blockDim.x + threadIdx.x;
    if (i < n) {
        int v = off[i] + bsum[i >> 10];
        off[i] = v;
        cursor[i] = v;
    }
}

__global__ void bin_k(const int* __restrict__ src, const int* __restrict__ dst, int e,
                      int* __restrict__ cursor, int* __restrict__ sorted) {
    int i = blockIdx.x * blockDim.x + threadIdx.x;
    if (i < e) {
        int d = dst[i];
        int pos = atomicAdd(&cursor[d], 1);
        sorted[pos] = src[i];
    }
}

// ---------------- GEMM1: hw1 = x @ W1 ----------------
// block = 512 threads = 8 rows x 64 cols (each wave owns one row)
__global__ void gemm1(const float* __restrict__ x, const float* __restrict__ W1,
                      float* __restrict__ hw1, int n) {
    __shared__ float Ws[IN_DIM * HID];   // 32 KB
    for (int i = threadIdx.x; i < IN_DIM * HID; i += blockDim.x) Ws[i] = W1[i];
    __syncthreads();
    int row = blockIdx.x * 8 + (threadIdx.x >> 6);
    int col = threadIdx.x & 63;
    if (row >= n) return;
    const float* xr = x + (size_t)row * IN_DIM;
    float acc = 0.f;
#pragma unroll 8
    for (int k = 0; k < IN_DIM; ++k) acc = fmaf(xr[k], Ws[k * HID + col], acc);
    hw1[(size_t)row * HID + col] = acc;
}

// ---------------- gather1: h[d] = dinv^2*hw1[d] + sum norm*hw1[src] ------------
// one wave per dst node, lane = column (HID=64)
__global__ void gather1(const float* __restrict__ hw1, const float* __restrict__ dinv,
                        const int* __restrict__ off, const int* __restrict__ sorted,
                        float* __restrict__ agg, int n) {
    int wid  = blockIdx.x * (blockDim.x >> 6) + (threadIdx.x >> 6);
    int lane = threadIdx.x & 63;
    if (wid >= n) return;
    float dd = dinv[wid];
    float acc = dd * dd * hw1[(size_t)wid * HID + lane];
    int b = off[wid], en = off[wid + 1];
    for (int j = b; j < en; ++j) {
        int s = sorted[j];
        acc = fmaf(dd * dinv[s], hw1[(size_t)s * HID + lane], acc);
    }
    agg[(size_t)wid * HID + lane] = acc;
}

// ---------------- GEMM2: hw2 = relu(h + b1) @ W2 ----------------
__global__ void gemm2(const float* __restrict__ h, const float* __restrict__ W2,
                      const float* __restrict__ b1, float* __restrict__ hw2, int n) {
    __shared__ float Ws[HID * OUT_DIM];
    __shared__ float hs[8][HID];
    for (int i = threadIdx.x; i < HID * OUT_DIM; i += blockDim.x) Ws[i] = W2[i];
    int base = blockIdx.x * 8;
    for (int i = threadIdx.x; i < 8 * HID; i += blockDim.x) {
        int r = i >> 6, k = i & 63;
        int gr = base + r;
        float v = 0.f;
        if (gr < n) v = fmaxf(h[(size_t)gr * HID + k] + b1[k], 0.f);
        hs[r][k] = v;
    }
    __syncthreads();
    int lr  = threadIdx.x / OUT_DIM;
    int col = threadIdx.x - lr * OUT_DIM;
    int row = base + lr;
    if (row >= n) return;
    float acc = 0.f;
#pragma unroll 8
    for (int k = 0; k < HID; ++k) acc = fmaf(hs[lr][k], Ws[k * OUT_DIM + col], acc);
    hw2[(size_t)row * OUT_DIM + col] = acc;
}

// ---------------- gather2 + finalize (bias + PKU + relu + log_softmax) ---------
__global__ void gather2_fin(const float* __restrict__ hw2, const float* __restrict__ dinv,
                            const int* __restrict__ off, const int* __restrict__ sorted,
                            const float* __restrict__ b2, const float* __restrict__ P,
                            const float* __restrict__ Kv, const float* __restrict__ U,
                            float* __restrict__ out, int n) {
    int wid  = blockIdx.x * (blockDim.x >> 6) + (threadIdx.x >> 6);
    int lane = threadIdx.x & 63;
    if (wid >= n) return;
    float dd = dinv[wid];
    float acc = 0.f;
    if (lane < OUT_DIM) acc = dd * dd * hw2[(size_t)wid * OUT_DIM + lane];
    int b = off[wid], en = off[wid + 1];
    for (int j = b; j < en; ++j) {
        int s = sorted[j];
        float nrm = dd * dinv[s];
        if (lane < OUT_DIM) acc = fmaf(nrm, hw2[(size_t)s * OUT_DIM + lane], acc);
    }
    float v = 0.f, y = -INFINITY;
    if (lane < OUT_DIM) {
        v = fmaxf(acc + b2[lane] + P[lane] * Kv[lane] * U[lane], 0.f);
        y = v;
    }
    float m = y;
#pragma unroll
    for (int o = 32; o; o >>= 1) m = fmaxf(m, __shfl_xor(m, o));
    float ex = (lane < OUT_DIM) ? __expf(v - m) : 0.f;
    float s2 = ex;
#pragma unroll
    for (int o = 32; o; o >>= 1) s2 += __shfl_xor(s2, o);
    float lse = m + __logf(s2);
    if (lane < OUT_DIM) out[(size_t)wid * OUT_DIM + lane] = v - lse;
}

extern "C" void kernel_launch(void* const* d_in, const int* in_sizes, int n_in,
                              void* d_out, int out_size, void* d_ws, size_t ws_size,
                              hipStream_t stream) {
    const float* x  = (const float*)d_in[0];
    const int*   ei = (const int*)d_in[1];
    const float* W1 = (const float*)d_in[2];
    const float* b1 = (const float*)d_in[3];
    const float* W2 = (const float*)d_in[4];
    const float* b2 = (const float*)d_in[5];
    const float* P  = (const float*)d_in[6];
    const float* K  = (const float*)d_in[7];
    const float* U  = (const float*)d_in[8];
    float* out = (float*)d_out;

    int n = in_sizes[0] / IN_DIM;   // 100000
    int e = in_sizes[1] / 2;        // 1600000
    const int* src = ei;
    const int* dst = ei + e;

    // workspace layout:
    // cnt[n] | dinv[n] | off[n+1] | cursor[n] | bsum[1024] | sorted[e] | hw1[n*64] | agg1[n*64]
    int*   cnt    = (int*)d_ws;
    float* dinv   = (float*)(cnt + n);
    int*   off    = (int*)(dinv + n);
    int*   cursor = off + (n + 1);
    int*   bsum   = cursor + n;
    int*   sorted = bsum + 1024;
    float* hw1    = (float*)(sorted + e);
    float* agg1   = hw1 + (size_t)n * HID;
    float* hw2    = hw1;   // reuse hw1 slot after gather1 (n*OUT_DIM < n*HID)

    int nb = (n + 1023) / 1024;  // 98

    hipMemsetAsync(cnt, 0, (size_t)n * sizeof(int), stream);
    count_k<<<(e + 255) / 256, 256, 0, stream>>>(dst, e, cnt);
    dinv_k<<<(n + 255) / 256, 256, 0, stream>>>(cnt, dinv, n);
    scan_local<<<nb, 256, 0, stream>>>(cnt, n, off, bsum);
    scan_bsum<<<1, 1024, 0, stream>>>(bsum, nb, n, off);
    scan_add<<<(n + 255) / 256, 256, 0, stream>>>(off, bsum, n, cursor);
    bin_k<<<(e + 255) / 256, 256, 0, stream>>>(src, dst, e, cursor, sorted);

    gemm1<<<(n + 7) / 8, 512, 0, stream>>>(x, W1, hw1, n);
    gather1<<<(n + 3) / 4, 256, 0, stream>>>(hw1, dinv, off, sorted, agg1, n);
    gemm2<<<(n + 7) / 8, 320, 0, stream>>>(agg1, W2, b1, hw2, n);
    gather2_fin<<<(n + 3) / 4, 256, 0, stream>>>(hw2, dinv, off, sorted,
                                                 b2, P, K, U, out, n);
}

// Round 4
// 515.773 us; speedup vs baseline: 5.1507x; 1.3393x over previous
//
#include <hip/hip_runtime.h>
#include <hip/hip_bf16.h>
#include <hip/hip_fp16.h>

#define IN_DIM 128
#define HID    64
#define OUT_DIM 40

// ---------------- degree count ----------------
__global__ void count_k(const int* __restrict__ dst, int e, int* __restrict__ cnt) {
    int i = blockIdx.x * blockDim.x + threadIdx.x;
    if (i < e) atomicAdd(&cnt[dst[i]], 1);
}

__global__ void dinv_k(const int* __restrict__ cnt, float* __restrict__ dinv, int n) {
    int i = blockIdx.x * blockDim.x + threadIdx.x;
    if (i < n) dinv[i] = rsqrtf((float)cnt[i] + 1.0f);
}

// ---------------- hierarchical exclusive scan ----------------
__global__ void scan_local(const int* __restrict__ cnt, int n,
                           int* __restrict__ off, int* __restrict__ bsum) {
    __shared__ int tmp[256];
    int t = threadIdx.x;
    int i0 = blockIdx.x * 1024 + t * 4;
    int c0 = (i0 + 0 < n) ? cnt[i0 + 0] : 0;
    int c1 = (i0 + 1 < n) ? cnt[i0 + 1] : 0;
    int c2 = (i0 + 2 < n) ? cnt[i0 + 2] : 0;
    int c3 = (i0 + 3 < n) ? cnt[i0 + 3] : 0;
    int s = c0 + c1 + c2 + c3;
    tmp[t] = s;
    __syncthreads();
    for (int ofs = 1; ofs < 256; ofs <<= 1) {
        int add = (t >= ofs) ? tmp[t - ofs] : 0;
        __syncthreads();
        tmp[t] += add;
        __syncthreads();
    }
    int run = tmp[t] - s;
    if (i0 + 0 < n) off[i0 + 0] = run; run += c0;
    if (i0 + 1 < n) off[i0 + 1] = run; run += c1;
    if (i0 + 2 < n) off[i0 + 2] = run; run += c2;
    if (i0 + 3 < n) off[i0 + 3] = run;
    if (t == 255) bsum[blockIdx.x] = tmp[255];
}

__global__ void scan_bsum(int* __restrict__ bsum, int nb, int n, int* __restrict__ off) {
    __shared__ int tmp[1024];
    int t = threadIdx.x;
    int v = (t < nb) ? bsum[t] : 0;
    tmp[t] = v;
    __syncthreads();
    for (int ofs = 1; ofs < 1024; ofs <<= 1) {
        int add = (t >= ofs) ? tmp[t - ofs] : 0;
        __syncthreads();
        tmp[t] += add;
        __syncthreads();
    }
    if (t < nb) bsum[t] = tmp[t] - v;
    if (t == 1023) off[n] = tmp[1023];
}

__global__ void scan_add(int* __restrict__ off, const int* __restrict__ bsum,
                         int n, int* __restrict__ cursor) {
    int i = blockIdx.x * blockDim.x + threadIdx.x;
    if (i < n) {
        int v = off[i] + bsum[i >> 10];
        off[i] = v;
        cursor[i] = v;
    }
}

__global__ void bin_k(const int* __restrict__ src, const int* __restrict__ dst, int e,
                      int* __restrict__ cursor, int* __restrict__ sorted) {
    int i = blockIdx.x * blockDim.x + threadIdx.x;
    if (i < e) {
        int d = dst[i];
        int pos = atomicAdd(&cursor[d], 1);
        sorted[pos] = src[i];
    }
}

// ---------------- GEMM1: hw1 = fp16(x @ W1) ----------------
__global__ void gemm1(const float* __restrict__ x, const float* __restrict__ W1,
                      __half* __restrict__ hw1, int n) {
    __shared__ float Ws[IN_DIM * HID];   // 32 KB
    for (int i = threadIdx.x; i < IN_DIM * HID; i += blockDim.x) Ws[i] = W1[i];
    __syncthreads();
    int row = blockIdx.x * 8 + (threadIdx.x >> 6);
    int col = threadIdx.x & 63;
    if (row >= n) return;
    const float* xr = x + (size_t)row * IN_DIM;
    float acc = 0.f;
#pragma unroll 8
    for (int k = 0; k < IN_DIM; ++k) acc = fmaf(xr[k], Ws[k * HID + col], acc);
    hw1[(size_t)row * HID + col] = __float2half(acc);
}

// ---------------- gather1: agg[d] = dinv^2*hw1[d] + sum norm*hw1[src] ----------
// one wave per dst node, lane = column (HID=64); 4x unrolled for MLP
__global__ void gather1(const __half* __restrict__ hw1, const float* __restrict__ dinv,
                        const int* __restrict__ off, const int* __restrict__ sorted,
                        float* __restrict__ agg, int n) {
    int wid  = blockIdx.x * (blockDim.x >> 6) + (threadIdx.x >> 6);
    int lane = threadIdx.x & 63;
    if (wid >= n) return;
    float dd = dinv[wid];
    float acc = dd * dd * __half2float(hw1[(size_t)wid * HID + lane]);
    int j = off[wid], en = off[wid + 1];
    for (; j + 4 <= en; j += 4) {
        int s0 = sorted[j + 0], s1 = sorted[j + 1];
        int s2 = sorted[j + 2], s3 = sorted[j + 3];
        float w0 = dinv[s0], w1 = dinv[s1], w2 = dinv[s2], w3 = dinv[s3];
        float v0 = __half2float(hw1[(size_t)s0 * HID + lane]);
        float v1 = __half2float(hw1[(size_t)s1 * HID + lane]);
        float v2 = __half2float(hw1[(size_t)s2 * HID + lane]);
        float v3 = __half2float(hw1[(size_t)s3 * HID + lane]);
        acc = fmaf(dd * w0, v0, acc);
        acc = fmaf(dd * w1, v1, acc);
        acc = fmaf(dd * w2, v2, acc);
        acc = fmaf(dd * w3, v3, acc);
    }
    for (; j < en; ++j) {
        int s = sorted[j];
        acc = fmaf(dd * dinv[s], __half2float(hw1[(size_t)s * HID + lane]), acc);
    }
    agg[(size_t)wid * HID + lane] = acc;
}

// ---------------- GEMM2: hw2 = fp16(relu(h + b1) @ W2) ----------------
__global__ void gemm2(const float* __restrict__ h, const float* __restrict__ W2,
                      const float* __restrict__ b1, __half* __restrict__ hw2, int n) {
    __shared__ float Ws[HID * OUT_DIM];
    __shared__ float hs[8][HID];
    for (int i = threadIdx.x; i < HID * OUT_DIM; i += blockDim.x) Ws[i] = W2[i];
    int base = blockIdx.x * 8;
    for (int i = threadIdx.x; i < 8 * HID; i += blockDim.x) {
        int r = i >> 6, k = i & 63;
        int gr = base + r;
        float v = 0.f;
        if (gr < n) v = fmaxf(h[(size_t)gr * HID + k] + b1[k], 0.f);
        hs[r][k] = v;
    }
    __syncthreads();
    int lr  = threadIdx.x / OUT_DIM;
    int col = threadIdx.x - lr * OUT_DIM;
    int row = base + lr;
    if (row >= n) return;
    float acc = 0.f;
#pragma unroll 8
    for (int k = 0; k < HID; ++k) acc = fmaf(hs[lr][k], Ws[k * OUT_DIM + col], acc);
    hw2[(size_t)row * OUT_DIM + col] = __float2half(acc);
}

// ---------------- gather2 + finalize; 4x unrolled ----------------
__global__ void gather2_fin(const __half* __restrict__ hw2, const float* __restrict__ dinv,
                            const int* __restrict__ off, const int* __restrict__ sorted,
                            const float* __restrict__ b2, const float* __restrict__ P,
                            const float* __restrict__ Kv, const float* __restrict__ U,
                            float* __restrict__ out, int n) {
    int wid  = blockIdx.x * (blockDim.x >> 6) + (threadIdx.x >> 6);
    int lane = threadIdx.x & 63;
    if (wid >= n) return;
    float dd = dinv[wid];
    int cl = (lane < OUT_DIM) ? lane : 0;  // clamp so idle lanes load safely
    float acc = dd * dd * __half2float(hw2[(size_t)wid * OUT_DIM + cl]);
    int j = off[wid], en = off[wid + 1];
    for (; j + 4 <= en; j += 4) {
        int s0 = sorted[j + 0], s1 = sorted[j + 1];
        int s2 = sorted[j + 2], s3 = sorted[j + 3];
        float w0 = dinv[s0], w1 = dinv[s1], w2 = dinv[s2], w3 = dinv[s3];
        float v0 = __half2float(hw2[(size_t)s0 * OUT_DIM + cl]);
        float v1 = __half2float(hw2[(size_t)s1 * OUT_DIM + cl]);
        float v2 = __half2float(hw2[(size_t)s2 * OUT_DIM + cl]);
        float v3 = __half2float(hw2[(size_t)s3 * OUT_DIM + cl]);
        acc = fmaf(dd * w0, v0, acc);
        acc = fmaf(dd * w1, v1, acc);
        acc = fmaf(dd * w2, v2, acc);
        acc = fmaf(dd * w3, v3, acc);
    }
    for (; j < en; ++j) {
        int s = sorted[j];
        acc = fmaf(dd * dinv[s], __half2float(hw2[(size_t)s * OUT_DIM + cl]), acc);
    }
    float v = 0.f, y = -INFINITY;
    if (lane < OUT_DIM) {
        v = fmaxf(acc + b2[lane] + P[lane] * Kv[lane] * U[lane], 0.f);
        y = v;
    }
    float m = y;
#pragma unroll
    for (int o = 32; o; o >>= 1) m = fmaxf(m, __shfl_xor(m, o));
    float ex = (lane < OUT_DIM) ? __expf(v - m) : 0.f;
    float s2 = ex;
#pragma unroll
    for (int o = 32; o; o >>= 1) s2 += __shfl_xor(s2, o);
    float lse = m + __logf(s2);
    if (lane < OUT_DIM) out[(size_t)wid * OUT_DIM + lane] = v - lse;
}

extern "C" void kernel_launch(void* const* d_in, const int* in_sizes, int n_in,
                              void* d_out, int out_size, void* d_ws, size_t ws_size,
                              hipStream_t stream) {
    const float* x  = (const float*)d_in[0];
    const int*   ei = (const int*)d_in[1];
    const float* W1 = (const float*)d_in[2];
    const float* b1 = (const float*)d_in[3];
    const float* W2 = (const float*)d_in[4];
    const float* b2 = (const float*)d_in[5];
    const float* P  = (const float*)d_in[6];
    const float* K  = (const float*)d_in[7];
    const float* U  = (const float*)d_in[8];
    float* out = (float*)d_out;

    int n = in_sizes[0] / IN_DIM;   // 100000
    int e = in_sizes[1] / 2;        // 1600000
    const int* src = ei;
    const int* dst = ei + e;

    // workspace layout:
    // cnt[n] | dinv[n] | off[n+1] | cursor[n] | bsum[1024] | sorted[e]
    //   | hw1 fp16 [n*64] | agg1 f32 [n*64]
    int*    cnt    = (int*)d_ws;
    float*  dinv   = (float*)(cnt + n);
    int*    off    = (int*)(dinv + n);
    int*    cursor = off + (n + 1);
    int*    bsum   = cursor + n;
    int*    sorted = bsum + 1024;
    __half* hw1    = (__half*)(sorted + e);
    float*  agg1   = (float*)(hw1 + (size_t)n * HID);
    __half* hw2    = hw1;   // reuse hw1 slot (n*OUT_DIM*2B < n*HID*2B)

    int nb = (n + 1023) / 1024;  // 98

    hipMemsetAsync(cnt, 0, (size_t)n * sizeof(int), stream);
    count_k<<<(e + 255) / 256, 256, 0, stream>>>(dst, e, cnt);
    dinv_k<<<(n + 255) / 256, 256, 0, stream>>>(cnt, dinv, n);
    scan_local<<<nb, 256, 0, stream>>>(cnt, n, off, bsum);
    scan_bsum<<<1, 1024, 0, stream>>>(bsum, nb, n, off);
    scan_add<<<(n + 255) / 256, 256, 0, stream>>>(off, bsum, n, cursor);
    bin_k<<<(e + 255) / 256, 256, 0, stream>>>(src, dst, e, cursor, sorted);

    gemm1<<<(n + 7) / 8, 512, 0, stream>>>(x, W1, hw1, n);
    gather1<<<(n + 3) / 4, 256, 0, stream>>>(hw1, dinv, off, sorted, agg1, n);
    gemm2<<<(n + 7) / 8, 320, 0, stream>>>(agg1, W2, b1, hw2, n);
    gather2_fin<<<(n + 3) / 4, 256, 0, stream>>>(hw2, dinv, off, sorted,
                                                 b2, P, K, U, out, n);
}